// Round 9
// baseline (99.775 us; speedup 1.0000x reference)
//
#include <hip/hip_runtime.h>
#include <math.h>

#define BATCH 32
#define NSAMP 262144
#define NKNOT 256
#define EPSV  0.001f
#define CH    16                  // samples per chunk (per thread)
#define CPB   256                 // chunks per block (= threads)
#define SPB   (CH * CPB)          // 4096 samples per block
#define NCROW (NSAMP / CH)        // 16384 chunks per row
#define BPR   (NCROW / CPB)       // 64 blocks per row
#define NB    (BATCH * BPR)       // 2048 blocks
#define NWAVE (CPB / 64)          // 4 waves
#define TS    (CPB + 2)           // 258 ≡ 2 (mod 32): transposed tile conflict-free

#define SCOPE_AGENT __HIP_MEMORY_SCOPE_AGENT

__device__ __forceinline__ float fast_tanh(float x) {
    // tanh(x) = 1 - 2/(exp(2x)+1); branch-free, ~1e-7 abs error
    float e = __expf(2.0f * x);
    float r = __builtin_amdgcn_rcpf(e + 1.0f);
    return fmaf(-2.0f, r, 1.0f);
}

__global__ __launch_bounds__(256, 3) void k_fused(
    const float* __restrict__ x,
    const float* __restrict__ cl,       // [BATCH][NKNOT][5]
    float* __restrict__ aggD,           // [NB][6]
    unsigned int* __restrict__ flags,   // [NB], zeroed per call
    float* __restrict__ out)
{
    __shared__ float tP[CH][TS];        // x, then P  (16.5 KB)
    __shared__ float tA[CH][TS];        // alpha      (16.5 KB)
    __shared__ float tB[CH][TS];        // beta       (16.5 KB)
    __shared__ float sC[2][CPB];        // per-chunk start states (2 KB)
    __shared__ float wag[NWAVE][6];
    __shared__ float sInit[2];
    const int tid = threadIdx.x;
    const int b = blockIdx.x;
    const int lane = tid & 63, wid = tid >> 6;

    // ---- Phase 0: coalesced global load -> transposed LDS (x into tP) ----
    const float4* x4 = (const float4*)x + (size_t)b * (SPB / 4);
    #pragma unroll
    for (int i = 0; i < 4; ++i) {
        int ii = tid + i * CPB;
        float4 v = x4[ii];
        int cc = ii >> 2, qq = (ii & 3) << 2;
        tP[qq + 0][cc] = v.x;
        tP[qq + 1][cc] = v.y;
        tP[qq + 2][cc] = v.z;
        tP[qq + 3][cc] = v.w;
    }

    // ---- knot coefficients (all 5 channels) + deltas ----
    int chunk = b * CPB + tid;
    int r = chunk >> 14;                 // / NCROW
    int c = chunk & (NCROW - 1);
    const float scale = 255.0f / 262143.0f;
    float pos0 = (float)(c * CH) * scale;
    float fiA = floorf(pos0);
    int idxA = (int)fiA;
    float w0v = pos0 - fiA;
    const float* kb = cl + (size_t)r * NKNOT * 5;
    int i1 = min(idxA + 1, NKNOT - 1);
    int i2 = min(idxA + 2, NKNOT - 1);
    float k00 = kb[idxA*5+0], k01 = kb[i1*5+0], k02 = kb[i2*5+0];
    float k10 = kb[idxA*5+1], k11 = kb[i1*5+1], k12 = kb[i2*5+1];
    float k20 = kb[idxA*5+2], k21 = kb[i1*5+2], k22 = kb[i2*5+2];
    float k30 = kb[idxA*5+3], k31 = kb[i1*5+3], k32 = kb[i2*5+3];
    float k40 = kb[idxA*5+4], k41 = kb[i1*5+4], k42 = kb[i2*5+4];
    float d0A = k01-k00, d0B = k02-k01;
    float d1A = k11-k10, d1B = k12-k11;
    float d2A = k21-k20, d2B = k22-k21;
    float d3A = k31-k30, d3B = k32-k31;
    float d4A = k41-k40, d4B = k42-k41;

    __syncthreads();

    // ---- Phase 1: SINGLE heavy pass — build map + emit P, alpha, beta ----
    const float stab = 1.0f - EPSV, stab2 = 2.0f * stab;
    float p1 = 0.f, p2 = 0.f;      // particular history (y(-1)=s0 seeds below)
    float A1 = 1.f, A2 = 0.f;      // d y / d s0 history
    float B1 = 0.f, B2 = 1.f;      // d y / d s1 history
    #pragma unroll
    for (int j = 0; j < CH; ++j) {
        float xs = tP[j][tid];
        float w = fmaf((float)j, scale, w0v);
        bool sel = w >= 1.0f;
        float wu = sel ? w - 1.0f : w;
        float l0 = fmaf(wu, sel ? d0B : d0A, sel ? k01 : k00);
        float l1 = fmaf(wu, sel ? d1B : d1A, sel ? k11 : k10);
        float b0 = fmaf(wu, sel ? d2B : d2A, sel ? k21 : k20);
        float b1c= fmaf(wu, sel ? d3B : d3A, sel ? k31 : k30);
        float b2c= fmaf(wu, sel ? d4B : d4A, sel ? k41 : k40);
        float th0 = fast_tanh(l0);
        float th1 = fast_tanh(l1);
        float a1 = stab2 * th0;
        float a1a = fabsf(a1);
        float a2 = 0.5f * fmaf((2.0f - a1a) * stab, th1, a1a);
        float p  = fmaf(-a2, p2, xs);  p = fmaf(-a1, p1, p);
        float hA = fmaf(-a1, A1, -a2 * A2);
        float hB = fmaf(-a1, B1, -a2 * B2);
        tP[j][tid] = fmaf(b0, p,  fmaf(b1c, p1, b2c * p2));   // P_j
        tA[j][tid] = fmaf(b0, hA, fmaf(b1c, A1, b2c * A2));   // alpha_j
        tB[j][tid] = fmaf(b0, hB, fmaf(b1c, B1, b2c * B2));   // beta_j
        p2 = p1; p1 = p;
        A2 = A1; A1 = hA;
        B2 = B1; B1 = hB;
    }
    // per-chunk affine map: s_end = [[A1,B1],[A2,B2]] s + (p1,p2)
    float L00 = A1, L01 = B1, L10 = A2, L11 = B2, Lv0 = p1, Lv1 = p2;

    // ---- Phase 2: intra-block affine scan ----
    #pragma unroll
    for (int d = 1; d < 64; d <<= 1) {
        float o00 = __shfl_up(L00, d), o01 = __shfl_up(L01, d);
        float o10 = __shfl_up(L10, d), o11 = __shfl_up(L11, d);
        float ov0 = __shfl_up(Lv0, d), ov1 = __shfl_up(Lv1, d);
        if (lane >= d) {
            float n00 = L00 * o00 + L01 * o10;
            float n01 = L00 * o01 + L01 * o11;
            float n10 = L10 * o00 + L11 * o10;
            float n11 = L10 * o01 + L11 * o11;
            float nv0 = fmaf(L00, ov0, fmaf(L01, ov1, Lv0));
            float nv1 = fmaf(L10, ov0, fmaf(L11, ov1, Lv1));
            L00 = n00; L01 = n01; L10 = n10; L11 = n11; Lv0 = nv0; Lv1 = nv1;
        }
    }
    if (lane == 63) {
        wag[wid][0] = L00; wag[wid][1] = L01; wag[wid][2] = L10;
        wag[wid][3] = L11; wag[wid][4] = Lv0; wag[wid][5] = Lv1;
    }
    __syncthreads();
    // P = compose of earlier waves' aggregates
    float P00 = 1.f, P01 = 0.f, P10 = 0.f, P11 = 1.f, Pv0 = 0.f, Pv1 = 0.f;
    for (int w2 = 0; w2 < wid; ++w2) {
        float a00 = wag[w2][0], a01 = wag[w2][1], a10 = wag[w2][2];
        float a11 = wag[w2][3], av0 = wag[w2][4], av1 = wag[w2][5];
        float n00 = a00 * P00 + a01 * P10;
        float n01 = a00 * P01 + a01 * P11;
        float n10 = a10 * P00 + a11 * P10;
        float n11 = a10 * P01 + a11 * P11;
        float nv0 = fmaf(a00, Pv0, fmaf(a01, Pv1, av0));
        float nv1 = fmaf(a10, Pv0, fmaf(a11, Pv1, av1));
        P00 = n00; P01 = n01; P10 = n10; P11 = n11; Pv0 = nv0; Pv1 = nv1;
    }
    // in-wave exclusive E; C = E ∘ P
    float E00 = __shfl_up(L00, 1), E01 = __shfl_up(L01, 1);
    float E10 = __shfl_up(L10, 1), E11 = __shfl_up(L11, 1);
    float Ev0 = __shfl_up(Lv0, 1), Ev1 = __shfl_up(Lv1, 1);
    if (lane == 0) { E00 = 1.f; E01 = 0.f; E10 = 0.f; E11 = 1.f; Ev0 = 0.f; Ev1 = 0.f; }
    float C00 = E00 * P00 + E01 * P10;
    float C01 = E00 * P01 + E01 * P11;
    float C10 = E10 * P00 + E11 * P10;
    float C11 = E10 * P01 + E11 * P11;
    float Cv0 = fmaf(E00, Pv0, fmaf(E01, Pv1, Ev0));
    float Cv1 = fmaf(E10, Pv0, fmaf(E11, Pv1, Ev1));

    // ---- publish block aggregate G = L(tid=255) ∘ P (release) ----
    if (tid == CPB - 1) {
        float G00 = L00 * P00 + L01 * P10;
        float G01 = L00 * P01 + L01 * P11;
        float G10 = L10 * P00 + L11 * P10;
        float G11 = L10 * P01 + L11 * P11;
        float Gv0 = fmaf(L00, Pv0, fmaf(L01, Pv1, Lv0));
        float Gv1 = fmaf(L10, Pv0, fmaf(L11, Pv1, Lv1));
        __hip_atomic_store(&aggD[b*6+0], G00, __ATOMIC_RELAXED, SCOPE_AGENT);
        __hip_atomic_store(&aggD[b*6+1], G01, __ATOMIC_RELAXED, SCOPE_AGENT);
        __hip_atomic_store(&aggD[b*6+2], G10, __ATOMIC_RELAXED, SCOPE_AGENT);
        __hip_atomic_store(&aggD[b*6+3], G11, __ATOMIC_RELAXED, SCOPE_AGENT);
        __hip_atomic_store(&aggD[b*6+4], Gv0, __ATOMIC_RELAXED, SCOPE_AGENT);
        __hip_atomic_store(&aggD[b*6+5], Gv1, __ATOMIC_RELAXED, SCOPE_AGENT);
        __hip_atomic_store(&flags[b], 1u, __ATOMIC_RELEASE, SCOPE_AGENT);
    }

    // ---- Phase 3: decoupled lookback (wave 0, one lane per predecessor) ----
    const int myIdx = b & (BPR - 1);
    const int rowFirst = b - myIdx;
    if (wid == 0) {
        float A00 = 1.f, A01 = 0.f, A10 = 0.f, A11 = 1.f, Av0 = 0.f, Av1 = 0.f;
        if (lane < myIdx) {
            int k = rowFirst + lane;
            while (__hip_atomic_load(&flags[k], __ATOMIC_ACQUIRE, SCOPE_AGENT) == 0u)
                __builtin_amdgcn_s_sleep(4);
            A00 = __hip_atomic_load(&aggD[k*6+0], __ATOMIC_RELAXED, SCOPE_AGENT);
            A01 = __hip_atomic_load(&aggD[k*6+1], __ATOMIC_RELAXED, SCOPE_AGENT);
            A10 = __hip_atomic_load(&aggD[k*6+2], __ATOMIC_RELAXED, SCOPE_AGENT);
            A11 = __hip_atomic_load(&aggD[k*6+3], __ATOMIC_RELAXED, SCOPE_AGENT);
            Av0 = __hip_atomic_load(&aggD[k*6+4], __ATOMIC_RELAXED, SCOPE_AGENT);
            Av1 = __hip_atomic_load(&aggD[k*6+5], __ATOMIC_RELAXED, SCOPE_AGENT);
        }
        #pragma unroll
        for (int d = 1; d < 64; d <<= 1) {
            float o00 = __shfl_up(A00, d), o01 = __shfl_up(A01, d);
            float o10 = __shfl_up(A10, d), o11 = __shfl_up(A11, d);
            float ov0 = __shfl_up(Av0, d), ov1 = __shfl_up(Av1, d);
            if (lane >= d) {
                float n00 = A00 * o00 + A01 * o10;
                float n01 = A00 * o01 + A01 * o11;
                float n10 = A10 * o00 + A11 * o10;
                float n11 = A10 * o01 + A11 * o11;
                float nv0 = fmaf(A00, ov0, fmaf(A01, ov1, Av0));
                float nv1 = fmaf(A10, ov0, fmaf(A11, ov1, Av1));
                A00 = n00; A01 = n01; A10 = n10; A11 = n11; Av0 = nv0; Av1 = nv1;
            }
        }
        float s0 = 0.f, s1 = 0.f;
        if (myIdx > 0) {
            s0 = __shfl(Av0, myIdx - 1);
            s1 = __shfl(Av1, myIdx - 1);
        }
        if (lane == 0) { sInit[0] = s0; sInit[1] = s1; }
    }
    __syncthreads();

    // ---- Phase 4: per-chunk start states into LDS ----
    {
        float s0 = sInit[0], s1 = sInit[1];
        sC[0][tid] = fmaf(C00, s0, fmaf(C01, s1, Cv0));
        sC[1][tid] = fmaf(C10, s0, fmaf(C11, s1, Cv1));
    }
    __syncthreads();

    // ---- Phase 5: light correction + coalesced float4 store ----
    float4* out4 = (float4*)out + (size_t)b * (SPB / 4);
    #pragma unroll
    for (int i = 0; i < 4; ++i) {
        int ii = tid + i * CPB;
        int cc = ii >> 2, qq = (ii & 3) << 2;
        float s0c = sC[0][cc], s1c = sC[1][cc];
        float4 v;
        v.x = fmaf(tA[qq+0][cc], s0c, fmaf(tB[qq+0][cc], s1c, tP[qq+0][cc]));
        v.y = fmaf(tA[qq+1][cc], s0c, fmaf(tB[qq+1][cc], s1c, tP[qq+1][cc]));
        v.z = fmaf(tA[qq+2][cc], s0c, fmaf(tB[qq+2][cc], s1c, tP[qq+2][cc]));
        v.w = fmaf(tA[qq+3][cc], s0c, fmaf(tB[qq+3][cc], s1c, tP[qq+3][cc]));
        out4[ii] = v;
    }
}

extern "C" void kernel_launch(void* const* d_in, const int* in_sizes, int n_in,
                              void* d_out, int out_size, void* d_ws, size_t ws_size,
                              hipStream_t stream) {
    const float* x  = (const float*)d_in[0];   // [32][262144]
    const float* cl = (const float*)d_in[1];   // [32][256][5]
    float* out = (float*)d_out;
    float* aggD = (float*)d_ws;                        // NB*6 floats
    unsigned int* flags = (unsigned int*)(aggD + (size_t)NB * 6);  // NB uints

    hipMemsetAsync(flags, 0, NB * sizeof(unsigned int), stream);
    hipLaunchKernelGGL(k_fused, dim3(NB), dim3(256), 0, stream,
                       x, cl, aggD, flags, out);
}

// Round 10
// 40.606 us; speedup vs baseline: 2.4572x; 2.4572x over previous
//
#include <hip/hip_runtime.h>
#include <math.h>

#define BATCH 32
#define NSAMP 262144
#define NKNOT 256
#define EPSV  0.001f
#define CH    16                  // samples per chunk = 64 B = one cache line
#define CPB   256                 // chunks per block (= threads)
#define NCROW (NSAMP / CH)        // 16384 chunks per row
#define BPR   (NCROW / CPB)       // 64 blocks per row (one wave scans it)
#define NB    (BATCH * BPR)       // 2048 blocks
#define NWAVE (CPB / 64)          // 4 waves per block

__device__ __forceinline__ float fast_tanh(float x) {
    // tanh(x) = 1 - 2/(exp(2x)+1); branch-free, ~1e-7 abs error
    float e = __expf(2.0f * x);
    float r = __builtin_amdgcn_rcpf(e + 1.0f);
    return fmaf(-2.0f, r, 1.0f);
}

// ---------------------------------------------------------------------------
// Kernel 1: per-block aggregate affine map G (transposed [6][NB]); no x-tile
// ---------------------------------------------------------------------------
__global__ __launch_bounds__(256, 4) void k_agg(
    const float* __restrict__ x,
    const float* __restrict__ cl,     // [BATCH][NKNOT][5]
    float* __restrict__ G)            // [6][NB]
{
    __shared__ float wag[NWAVE][6];
    const int tid = threadIdx.x;
    const int b = blockIdx.x;
    const int lane = tid & 63, wid = tid >> 6;

    // direct per-thread chunk load: 64 B/thread, wave covers contiguous 4 KB
    int chunk = b * CPB + tid;
    const float4* xp = (const float4*)(x + (size_t)chunk * CH);
    float xr[CH];
    *(float4*)&xr[0]  = xp[0];
    *(float4*)&xr[4]  = xp[1];
    *(float4*)&xr[8]  = xp[2];
    *(float4*)&xr[12] = xp[3];

    // knot coefficients (channels 0,1)
    int r = chunk >> 14;                 // / NCROW
    int c = chunk & (NCROW - 1);
    const float scale = 255.0f / 262143.0f;
    float pos0 = (float)(c * CH) * scale;
    float fiA = floorf(pos0);
    int idxA = (int)fiA;
    float w0v = pos0 - fiA;
    const float* kb = cl + (size_t)r * NKNOT * 5;
    int i1 = min(idxA + 1, NKNOT - 1);
    int i2 = min(idxA + 2, NKNOT - 1);
    float k00 = kb[idxA*5+0], k01 = kb[i1*5+0], k02 = kb[i2*5+0];
    float k10 = kb[idxA*5+1], k11 = kb[i1*5+1], k12 = kb[i2*5+1];
    float d0A = k01-k00, d0B = k02-k01;
    float d1A = k11-k10, d1B = k12-k11;

    // build per-chunk affine map  s_end = M s_start + v
    const float stab = 1.0f - EPSV, stab2 = 2.0f * stab;
    float p1 = 0.f, p2 = 0.f, A1 = 1.f, A2 = 0.f, B1 = 0.f, B2 = 1.f;
    #pragma unroll
    for (int j = 0; j < CH; ++j) {
        float w = fmaf((float)j, scale, w0v);
        bool sel = w >= 1.0f;
        float wu = sel ? w - 1.0f : w;
        float l0 = fmaf(wu, sel ? d0B : d0A, sel ? k01 : k00);
        float l1 = fmaf(wu, sel ? d1B : d1A, sel ? k11 : k10);
        float a1 = stab2 * fast_tanh(l0);
        float a1a = fabsf(a1);
        float a2 = 0.5f * fmaf((2.0f - a1a) * stab, fast_tanh(l1), a1a);
        float p  = fmaf(-a2, p2, xr[j]);  p = fmaf(-a1, p1, p);
        float hA = fmaf(-a1, A1, -a2 * A2);
        float hB = fmaf(-a1, B1, -a2 * B2);
        p2 = p1; p1 = p;
        A2 = A1; A1 = hA;
        B2 = B1; B1 = hB;
    }
    float L00 = A1, L01 = B1, L10 = A2, L11 = B2, Lv0 = p1, Lv1 = p2;

    // wave-inclusive scan (compose later ∘ earlier)
    #pragma unroll
    for (int d = 1; d < 64; d <<= 1) {
        float o00 = __shfl_up(L00, d), o01 = __shfl_up(L01, d);
        float o10 = __shfl_up(L10, d), o11 = __shfl_up(L11, d);
        float ov0 = __shfl_up(Lv0, d), ov1 = __shfl_up(Lv1, d);
        if (lane >= d) {
            float n00 = L00 * o00 + L01 * o10;
            float n01 = L00 * o01 + L01 * o11;
            float n10 = L10 * o00 + L11 * o10;
            float n11 = L10 * o01 + L11 * o11;
            float nv0 = fmaf(L00, ov0, fmaf(L01, ov1, Lv0));
            float nv1 = fmaf(L10, ov0, fmaf(L11, ov1, Lv1));
            L00 = n00; L01 = n01; L10 = n10; L11 = n11; Lv0 = nv0; Lv1 = nv1;
        }
    }
    if (lane == 63) {
        wag[wid][0] = L00; wag[wid][1] = L01; wag[wid][2] = L10;
        wag[wid][3] = L11; wag[wid][4] = Lv0; wag[wid][5] = Lv1;
    }
    __syncthreads();

    // last thread composes wave aggregates -> block aggregate
    if (tid == CPB - 1) {
        float P00 = 1.f, P01 = 0.f, P10 = 0.f, P11 = 1.f, Pv0 = 0.f, Pv1 = 0.f;
        for (int w2 = 0; w2 < NWAVE - 1; ++w2) {
            float a00 = wag[w2][0], a01 = wag[w2][1], a10 = wag[w2][2];
            float a11 = wag[w2][3], av0 = wag[w2][4], av1 = wag[w2][5];
            float n00 = a00 * P00 + a01 * P10;
            float n01 = a00 * P01 + a01 * P11;
            float n10 = a10 * P00 + a11 * P10;
            float n11 = a10 * P01 + a11 * P11;
            float nv0 = fmaf(a00, Pv0, fmaf(a01, Pv1, av0));
            float nv1 = fmaf(a10, Pv0, fmaf(a11, Pv1, av1));
            P00 = n00; P01 = n01; P10 = n10; P11 = n11; Pv0 = nv0; Pv1 = nv1;
        }
        G[0*NB + b] = L00 * P00 + L01 * P10;
        G[1*NB + b] = L00 * P01 + L01 * P11;
        G[2*NB + b] = L10 * P00 + L11 * P10;
        G[3*NB + b] = L10 * P01 + L11 * P11;
        G[4*NB + b] = fmaf(L00, Pv0, fmaf(L01, Pv1, Lv0));
        G[5*NB + b] = fmaf(L10, Pv0, fmaf(L11, Pv1, Lv1));
    }
}

// ---------------------------------------------------------------------------
// Kernel 2: inline row-scan of G + rebuild + scan + apply + FIR; no tiles
// ---------------------------------------------------------------------------
__global__ __launch_bounds__(256, 4) void k_apply(
    const float* __restrict__ x,
    const float* __restrict__ cl,
    const float* __restrict__ G,      // [6][NB]
    float* __restrict__ out)
{
    __shared__ float wag[NWAVE][6];
    __shared__ float sInit[2];
    const int tid = threadIdx.x;
    const int b = blockIdx.x;
    const int lane = tid & 63, wid = tid >> 6;

    // wave 0: scan this row's 64 block aggregates -> block-start state
    if (wid == 0) {
        int rowFirst = b & ~(BPR - 1);
        int k = rowFirst + lane;
        float A00 = G[0*NB + k], A01 = G[1*NB + k], A10 = G[2*NB + k];
        float A11 = G[3*NB + k], Av0 = G[4*NB + k], Av1 = G[5*NB + k];
        #pragma unroll
        for (int d = 1; d < 64; d <<= 1) {
            float o00 = __shfl_up(A00, d), o01 = __shfl_up(A01, d);
            float o10 = __shfl_up(A10, d), o11 = __shfl_up(A11, d);
            float ov0 = __shfl_up(Av0, d), ov1 = __shfl_up(Av1, d);
            if (lane >= d) {
                float n00 = A00 * o00 + A01 * o10;
                float n01 = A00 * o01 + A01 * o11;
                float n10 = A10 * o00 + A11 * o10;
                float n11 = A10 * o01 + A11 * o11;
                float nv0 = fmaf(A00, ov0, fmaf(A01, ov1, Av0));
                float nv1 = fmaf(A10, ov0, fmaf(A11, ov1, Av1));
                A00 = n00; A01 = n01; A10 = n10; A11 = n11; Av0 = nv0; Av1 = nv1;
            }
        }
        int myIdx = b & (BPR - 1);
        int src = (myIdx > 0) ? myIdx - 1 : 0;
        float s0 = __shfl(Av0, src);
        float s1 = __shfl(Av1, src);
        if (lane == 0) {
            sInit[0] = myIdx ? s0 : 0.f;
            sInit[1] = myIdx ? s1 : 0.f;
        }
    }

    // direct per-thread chunk load, kept in registers across the scan
    int chunk = b * CPB + tid;
    const float4* xp = (const float4*)(x + (size_t)chunk * CH);
    float xr[CH];
    *(float4*)&xr[0]  = xp[0];
    *(float4*)&xr[4]  = xp[1];
    *(float4*)&xr[8]  = xp[2];
    *(float4*)&xr[12] = xp[3];

    // knot coefficients (all 5 channels)
    int r = chunk >> 14;
    int c = chunk & (NCROW - 1);
    const float scale = 255.0f / 262143.0f;
    float pos0 = (float)(c * CH) * scale;
    float fiA = floorf(pos0);
    int idxA = (int)fiA;
    float w0v = pos0 - fiA;
    const float* kb = cl + (size_t)r * NKNOT * 5;
    int i1 = min(idxA + 1, NKNOT - 1);
    int i2 = min(idxA + 2, NKNOT - 1);
    float k00 = kb[idxA*5+0], k01 = kb[i1*5+0], k02 = kb[i2*5+0];
    float k10 = kb[idxA*5+1], k11 = kb[i1*5+1], k12 = kb[i2*5+1];
    float k20 = kb[idxA*5+2], k21 = kb[i1*5+2], k22 = kb[i2*5+2];
    float k30 = kb[idxA*5+3], k31 = kb[i1*5+3], k32 = kb[i2*5+3];
    float k40 = kb[idxA*5+4], k41 = kb[i1*5+4], k42 = kb[i2*5+4];
    float d0A = k01-k00, d0B = k02-k01;
    float d1A = k11-k10, d1B = k12-k11;
    float d2A = k21-k20, d2B = k22-k21;
    float d3A = k31-k30, d3B = k32-k31;
    float d4A = k41-k40, d4B = k42-k41;

    // rebuild per-chunk affine map (a-channels only)
    const float stab = 1.0f - EPSV, stab2 = 2.0f * stab;
    float p1 = 0.f, p2 = 0.f, A1 = 1.f, A2 = 0.f, B1 = 0.f, B2 = 1.f;
    #pragma unroll
    for (int j = 0; j < CH; ++j) {
        float w = fmaf((float)j, scale, w0v);
        bool sel = w >= 1.0f;
        float wu = sel ? w - 1.0f : w;
        float l0 = fmaf(wu, sel ? d0B : d0A, sel ? k01 : k00);
        float l1 = fmaf(wu, sel ? d1B : d1A, sel ? k11 : k10);
        float a1 = stab2 * fast_tanh(l0);
        float a1a = fabsf(a1);
        float a2 = 0.5f * fmaf((2.0f - a1a) * stab, fast_tanh(l1), a1a);
        float p  = fmaf(-a2, p2, xr[j]);  p = fmaf(-a1, p1, p);
        float hA = fmaf(-a1, A1, -a2 * A2);
        float hB = fmaf(-a1, B1, -a2 * B2);
        p2 = p1; p1 = p;
        A2 = A1; A1 = hA;
        B2 = B1; B1 = hB;
    }
    float L00 = A1, L01 = B1, L10 = A2, L11 = B2, Lv0 = p1, Lv1 = p2;

    // wave-inclusive scan
    #pragma unroll
    for (int d = 1; d < 64; d <<= 1) {
        float o00 = __shfl_up(L00, d), o01 = __shfl_up(L01, d);
        float o10 = __shfl_up(L10, d), o11 = __shfl_up(L11, d);
        float ov0 = __shfl_up(Lv0, d), ov1 = __shfl_up(Lv1, d);
        if (lane >= d) {
            float n00 = L00 * o00 + L01 * o10;
            float n01 = L00 * o01 + L01 * o11;
            float n10 = L10 * o00 + L11 * o10;
            float n11 = L10 * o01 + L11 * o11;
            float nv0 = fmaf(L00, ov0, fmaf(L01, ov1, Lv0));
            float nv1 = fmaf(L10, ov0, fmaf(L11, ov1, Lv1));
            L00 = n00; L01 = n01; L10 = n10; L11 = n11; Lv0 = nv0; Lv1 = nv1;
        }
    }
    if (lane == 63) {
        wag[wid][0] = L00; wag[wid][1] = L01; wag[wid][2] = L10;
        wag[wid][3] = L11; wag[wid][4] = Lv0; wag[wid][5] = Lv1;
    }
    __syncthreads();
    // P = compose of earlier waves
    float P00 = 1.f, P01 = 0.f, P10 = 0.f, P11 = 1.f, Pv0 = 0.f, Pv1 = 0.f;
    for (int w2 = 0; w2 < wid; ++w2) {
        float a00 = wag[w2][0], a01 = wag[w2][1], a10 = wag[w2][2];
        float a11 = wag[w2][3], av0 = wag[w2][4], av1 = wag[w2][5];
        float n00 = a00 * P00 + a01 * P10;
        float n01 = a00 * P01 + a01 * P11;
        float n10 = a10 * P00 + a11 * P10;
        float n11 = a10 * P01 + a11 * P11;
        float nv0 = fmaf(a00, Pv0, fmaf(a01, Pv1, av0));
        float nv1 = fmaf(a10, Pv0, fmaf(a11, Pv1, av1));
        P00 = n00; P01 = n01; P10 = n10; P11 = n11; Pv0 = nv0; Pv1 = nv1;
    }
    // in-wave exclusive E; C = E ∘ P
    float E00 = __shfl_up(L00, 1), E01 = __shfl_up(L01, 1);
    float E10 = __shfl_up(L10, 1), E11 = __shfl_up(L11, 1);
    float Ev0 = __shfl_up(Lv0, 1), Ev1 = __shfl_up(Lv1, 1);
    if (lane == 0) { E00 = 1.f; E01 = 0.f; E10 = 0.f; E11 = 1.f; Ev0 = 0.f; Ev1 = 0.f; }
    float C00 = E00 * P00 + E01 * P10;
    float C01 = E00 * P01 + E01 * P11;
    float C10 = E10 * P00 + E11 * P10;
    float C11 = E10 * P01 + E11 * P11;
    float Cv0 = fmaf(E00, Pv0, fmaf(E01, Pv1, Ev0));
    float Cv1 = fmaf(E10, Pv0, fmaf(E11, Pv1, Ev1));

    float s0 = sInit[0], s1 = sInit[1];
    float y1 = fmaf(C00, s0, fmaf(C01, s1, Cv0));
    float y2 = fmaf(C10, s0, fmaf(C11, s1, Cv1));

    // apply recurrence + fused FIR, overwrite xr in place
    #pragma unroll
    for (int j = 0; j < CH; ++j) {
        float w = fmaf((float)j, scale, w0v);
        bool sel = w >= 1.0f;
        float wu = sel ? w - 1.0f : w;
        float l0 = fmaf(wu, sel ? d0B : d0A, sel ? k01 : k00);
        float l1 = fmaf(wu, sel ? d1B : d1A, sel ? k11 : k10);
        float b0 = fmaf(wu, sel ? d2B : d2A, sel ? k21 : k20);
        float b1c= fmaf(wu, sel ? d3B : d3A, sel ? k31 : k30);
        float b2c= fmaf(wu, sel ? d4B : d4A, sel ? k41 : k40);
        float a1 = stab2 * fast_tanh(l0);
        float a1a = fabsf(a1);
        float a2 = 0.5f * fmaf((2.0f - a1a) * stab, fast_tanh(l1), a1a);
        float y = fmaf(-a2, y2, xr[j]);  y = fmaf(-a1, y1, y);
        xr[j] = fmaf(b0, y, fmaf(b1c, y1, b2c * y2));
        y2 = y1; y1 = y;
    }

    // direct stores: 4 float4 = one 64 B line per thread, wave-contiguous 4 KB
    float4* op = (float4*)(out + (size_t)chunk * CH);
    op[0] = *(const float4*)&xr[0];
    op[1] = *(const float4*)&xr[4];
    op[2] = *(const float4*)&xr[8];
    op[3] = *(const float4*)&xr[12];
}

extern "C" void kernel_launch(void* const* d_in, const int* in_sizes, int n_in,
                              void* d_out, int out_size, void* d_ws, size_t ws_size,
                              hipStream_t stream) {
    const float* x  = (const float*)d_in[0];   // [32][262144]
    const float* cl = (const float*)d_in[1];   // [32][256][5]
    float* out = (float*)d_out;
    float* G = (float*)d_ws;                   // [6][NB] floats (48 KB)

    hipLaunchKernelGGL(k_agg,   dim3(NB), dim3(CPB), 0, stream, x, cl, G);
    hipLaunchKernelGGL(k_apply, dim3(NB), dim3(CPB), 0, stream, x, cl, G, out);
}

// Round 11
// 38.946 us; speedup vs baseline: 2.5619x; 1.0426x over previous
//
#include <hip/hip_runtime.h>
#include <math.h>

#define BATCH 32
#define NSAMP 262144
#define NKNOT 256
#define EPSV  0.001f
#define CH    16                  // samples per chunk = 64 B = one cache line
#define CPB   256                 // chunks per block (= threads)
#define NCROW (NSAMP / CH)        // 16384 chunks per row
#define BPR   (NCROW / CPB)       // 64 blocks per row (one wave scans it)
#define NB    (BATCH * BPR)       // 2048 blocks
#define TC    (NB * CPB)          // 524288 chunks total
#define NWAVE (CPB / 64)          // 4 waves per block

__device__ __forceinline__ float fast_tanh(float x) {
    // tanh(x) = 1 - 2/(exp(2x)+1); branch-free, ~1e-7 abs error
    float e = __expf(2.0f * x);
    float r = __builtin_amdgcn_rcpf(e + 1.0f);
    return fmaf(-2.0f, r, 1.0f);
}

// ---------------------------------------------------------------------------
// Kernel 1: per-chunk exclusive in-block prefix C[6][TC] + block aggregate G
// ---------------------------------------------------------------------------
__global__ __launch_bounds__(256, 4) void k_agg(
    const float* __restrict__ x,
    const float* __restrict__ cl,     // [BATCH][NKNOT][5]
    float* __restrict__ Cb,           // [6][TC]
    float* __restrict__ G)            // [6][NB]
{
    __shared__ float wag[NWAVE][6];
    const int tid = threadIdx.x;
    const int b = blockIdx.x;
    const int lane = tid & 63, wid = tid >> 6;

    int chunk = b * CPB + tid;
    const float4* xp = (const float4*)(x + (size_t)chunk * CH);

    // knot coefficients (channels 0,1)
    int r = chunk >> 14;                 // / NCROW
    int c = chunk & (NCROW - 1);
    const float scale = 255.0f / 262143.0f;
    float pos0 = (float)(c * CH) * scale;
    float fiA = floorf(pos0);
    int idxA = (int)fiA;
    float w0v = pos0 - fiA;
    const float* kb = cl + (size_t)r * NKNOT * 5;
    int i1 = min(idxA + 1, NKNOT - 1);
    int i2 = min(idxA + 2, NKNOT - 1);
    float k00 = kb[idxA*5+0], k01 = kb[i1*5+0], k02 = kb[i2*5+0];
    float k10 = kb[idxA*5+1], k11 = kb[i1*5+1], k12 = kb[i2*5+1];
    float d0A = k01-k00, d0B = k02-k01;
    float d1A = k11-k10, d1B = k12-k11;

    // build per-chunk affine map  s_end = M s_start + v (consume x inline)
    const float stab = 1.0f - EPSV, stab2 = 2.0f * stab;
    float p1 = 0.f, p2 = 0.f, A1 = 1.f, A2 = 0.f, B1 = 0.f, B2 = 1.f;
    #pragma unroll
    for (int v4 = 0; v4 < 4; ++v4) {
        float4 xq = xp[v4];
        #pragma unroll
        for (int q = 0; q < 4; ++q) {
            int j = v4 * 4 + q;
            float w = fmaf((float)j, scale, w0v);
            bool sel = w >= 1.0f;
            float wu = sel ? w - 1.0f : w;
            float l0 = fmaf(wu, sel ? d0B : d0A, sel ? k01 : k00);
            float l1 = fmaf(wu, sel ? d1B : d1A, sel ? k11 : k10);
            float a1 = stab2 * fast_tanh(l0);
            float a1a = fabsf(a1);
            float a2 = 0.5f * fmaf((2.0f - a1a) * stab, fast_tanh(l1), a1a);
            float p  = fmaf(-a2, p2, (&xq.x)[q]);  p = fmaf(-a1, p1, p);
            float hA = fmaf(-a1, A1, -a2 * A2);
            float hB = fmaf(-a1, B1, -a2 * B2);
            p2 = p1; p1 = p;
            A2 = A1; A1 = hA;
            B2 = B1; B1 = hB;
        }
    }
    float L00 = A1, L01 = B1, L10 = A2, L11 = B2, Lv0 = p1, Lv1 = p2;

    // wave-inclusive scan (compose later ∘ earlier)
    #pragma unroll
    for (int d = 1; d < 64; d <<= 1) {
        float o00 = __shfl_up(L00, d), o01 = __shfl_up(L01, d);
        float o10 = __shfl_up(L10, d), o11 = __shfl_up(L11, d);
        float ov0 = __shfl_up(Lv0, d), ov1 = __shfl_up(Lv1, d);
        if (lane >= d) {
            float n00 = L00 * o00 + L01 * o10;
            float n01 = L00 * o01 + L01 * o11;
            float n10 = L10 * o00 + L11 * o10;
            float n11 = L10 * o01 + L11 * o11;
            float nv0 = fmaf(L00, ov0, fmaf(L01, ov1, Lv0));
            float nv1 = fmaf(L10, ov0, fmaf(L11, ov1, Lv1));
            L00 = n00; L01 = n01; L10 = n10; L11 = n11; Lv0 = nv0; Lv1 = nv1;
        }
    }
    if (lane == 63) {
        wag[wid][0] = L00; wag[wid][1] = L01; wag[wid][2] = L10;
        wag[wid][3] = L11; wag[wid][4] = Lv0; wag[wid][5] = Lv1;
    }
    __syncthreads();

    // P = compose of earlier waves' aggregates
    float P00 = 1.f, P01 = 0.f, P10 = 0.f, P11 = 1.f, Pv0 = 0.f, Pv1 = 0.f;
    for (int w2 = 0; w2 < wid; ++w2) {
        float a00 = wag[w2][0], a01 = wag[w2][1], a10 = wag[w2][2];
        float a11 = wag[w2][3], av0 = wag[w2][4], av1 = wag[w2][5];
        float n00 = a00 * P00 + a01 * P10;
        float n01 = a00 * P01 + a01 * P11;
        float n10 = a10 * P00 + a11 * P10;
        float n11 = a10 * P01 + a11 * P11;
        float nv0 = fmaf(a00, Pv0, fmaf(a01, Pv1, av0));
        float nv1 = fmaf(a10, Pv0, fmaf(a11, Pv1, av1));
        P00 = n00; P01 = n01; P10 = n10; P11 = n11; Pv0 = nv0; Pv1 = nv1;
    }
    // in-wave exclusive E; C = E ∘ P (exclusive prefix from block start)
    float E00 = __shfl_up(L00, 1), E01 = __shfl_up(L01, 1);
    float E10 = __shfl_up(L10, 1), E11 = __shfl_up(L11, 1);
    float Ev0 = __shfl_up(Lv0, 1), Ev1 = __shfl_up(Lv1, 1);
    if (lane == 0) { E00 = 1.f; E01 = 0.f; E10 = 0.f; E11 = 1.f; Ev0 = 0.f; Ev1 = 0.f; }
    Cb[0*TC + chunk] = E00 * P00 + E01 * P10;
    Cb[1*TC + chunk] = E00 * P01 + E01 * P11;
    Cb[2*TC + chunk] = E10 * P00 + E11 * P10;
    Cb[3*TC + chunk] = E10 * P01 + E11 * P11;
    Cb[4*TC + chunk] = fmaf(E00, Pv0, fmaf(E01, Pv1, Ev0));
    Cb[5*TC + chunk] = fmaf(E10, Pv0, fmaf(E11, Pv1, Ev1));

    // block aggregate G = L(tid=255) ∘ P
    if (tid == CPB - 1) {
        G[0*NB + b] = L00 * P00 + L01 * P10;
        G[1*NB + b] = L00 * P01 + L01 * P11;
        G[2*NB + b] = L10 * P00 + L11 * P10;
        G[3*NB + b] = L10 * P01 + L11 * P11;
        G[4*NB + b] = fmaf(L00, Pv0, fmaf(L01, Pv1, Lv0));
        G[5*NB + b] = fmaf(L10, Pv0, fmaf(L11, Pv1, Lv1));
    }
}

// ---------------------------------------------------------------------------
// Kernel 2: row-scan of G (wave 0) + single apply+FIR pass using stored C
// ---------------------------------------------------------------------------
__global__ __launch_bounds__(256, 6) void k_apply(
    const float* __restrict__ x,
    const float* __restrict__ cl,
    const float* __restrict__ Cb,     // [6][TC]
    const float* __restrict__ G,      // [6][NB]
    float* __restrict__ out)
{
    __shared__ float sInit[2];
    const int tid = threadIdx.x;
    const int b = blockIdx.x;
    const int lane = tid & 63, wid = tid >> 6;

    // wave 0: scan this row's 64 block aggregates -> block-start state
    if (wid == 0) {
        int rowFirst = b & ~(BPR - 1);
        int k = rowFirst + lane;
        float A00 = G[0*NB + k], A01 = G[1*NB + k], A10 = G[2*NB + k];
        float A11 = G[3*NB + k], Av0 = G[4*NB + k], Av1 = G[5*NB + k];
        #pragma unroll
        for (int d = 1; d < 64; d <<= 1) {
            float o00 = __shfl_up(A00, d), o01 = __shfl_up(A01, d);
            float o10 = __shfl_up(A10, d), o11 = __shfl_up(A11, d);
            float ov0 = __shfl_up(Av0, d), ov1 = __shfl_up(Av1, d);
            if (lane >= d) {
                float n00 = A00 * o00 + A01 * o10;
                float n01 = A00 * o01 + A01 * o11;
                float n10 = A10 * o00 + A11 * o10;
                float n11 = A10 * o01 + A11 * o11;
                float nv0 = fmaf(A00, ov0, fmaf(A01, ov1, Av0));
                float nv1 = fmaf(A10, ov0, fmaf(A11, ov1, Av1));
                A00 = n00; A01 = n01; A10 = n10; A11 = n11; Av0 = nv0; Av1 = nv1;
            }
        }
        int myIdx = b & (BPR - 1);
        int src = (myIdx > 0) ? myIdx - 1 : 0;
        float s0 = __shfl(Av0, src);
        float s1 = __shfl(Av1, src);
        if (lane == 0) {
            sInit[0] = myIdx ? s0 : 0.f;
            sInit[1] = myIdx ? s1 : 0.f;
        }
    }

    // knot coefficients (all 5 channels)
    int chunk = b * CPB + tid;
    int r = chunk >> 14;
    int c = chunk & (NCROW - 1);
    const float scale = 255.0f / 262143.0f;
    float pos0 = (float)(c * CH) * scale;
    float fiA = floorf(pos0);
    int idxA = (int)fiA;
    float w0v = pos0 - fiA;
    const float* kb = cl + (size_t)r * NKNOT * 5;
    int i1 = min(idxA + 1, NKNOT - 1);
    int i2 = min(idxA + 2, NKNOT - 1);
    float k00 = kb[idxA*5+0], k01 = kb[i1*5+0], k02 = kb[i2*5+0];
    float k10 = kb[idxA*5+1], k11 = kb[i1*5+1], k12 = kb[i2*5+1];
    float k20 = kb[idxA*5+2], k21 = kb[i1*5+2], k22 = kb[i2*5+2];
    float k30 = kb[idxA*5+3], k31 = kb[i1*5+3], k32 = kb[i2*5+3];
    float k40 = kb[idxA*5+4], k41 = kb[i1*5+4], k42 = kb[i2*5+4];
    float d0A = k01-k00, d0B = k02-k01;
    float d1A = k11-k10, d1B = k12-k11;
    float d2A = k21-k20, d2B = k22-k21;
    float d3A = k31-k30, d3B = k32-k31;
    float d4A = k41-k40, d4B = k42-k41;

    // per-chunk C (coalesced loads)
    float C00 = Cb[0*TC + chunk], C01 = Cb[1*TC + chunk];
    float C10 = Cb[2*TC + chunk], C11 = Cb[3*TC + chunk];
    float Cv0 = Cb[4*TC + chunk], Cv1 = Cb[5*TC + chunk];

    __syncthreads();
    float s0 = sInit[0], s1 = sInit[1];
    float y1 = fmaf(C00, s0, fmaf(C01, s1, Cv0));
    float y2 = fmaf(C10, s0, fmaf(C11, s1, Cv1));

    // single apply+FIR pass (x consumed inline, out written inline)
    const float stab = 1.0f - EPSV, stab2 = 2.0f * stab;
    const float4* xp = (const float4*)(x + (size_t)chunk * CH);
    float4* op = (float4*)(out + (size_t)chunk * CH);
    #pragma unroll
    for (int v4 = 0; v4 < 4; ++v4) {
        float4 xq = xp[v4];
        float4 ov;
        #pragma unroll
        for (int q = 0; q < 4; ++q) {
            int j = v4 * 4 + q;
            float w = fmaf((float)j, scale, w0v);
            bool sel = w >= 1.0f;
            float wu = sel ? w - 1.0f : w;
            float l0 = fmaf(wu, sel ? d0B : d0A, sel ? k01 : k00);
            float l1 = fmaf(wu, sel ? d1B : d1A, sel ? k11 : k10);
            float b0 = fmaf(wu, sel ? d2B : d2A, sel ? k21 : k20);
            float b1c= fmaf(wu, sel ? d3B : d3A, sel ? k31 : k30);
            float b2c= fmaf(wu, sel ? d4B : d4A, sel ? k41 : k40);
            float a1 = stab2 * fast_tanh(l0);
            float a1a = fabsf(a1);
            float a2 = 0.5f * fmaf((2.0f - a1a) * stab, fast_tanh(l1), a1a);
            float y = fmaf(-a2, y2, (&xq.x)[q]);  y = fmaf(-a1, y1, y);
            (&ov.x)[q] = fmaf(b0, y, fmaf(b1c, y1, b2c * y2));
            y2 = y1; y1 = y;
        }
        op[v4] = ov;
    }
}

extern "C" void kernel_launch(void* const* d_in, const int* in_sizes, int n_in,
                              void* d_out, int out_size, void* d_ws, size_t ws_size,
                              hipStream_t stream) {
    const float* x  = (const float*)d_in[0];   // [32][262144]
    const float* cl = (const float*)d_in[1];   // [32][256][5]
    float* out = (float*)d_out;
    float* Cb = (float*)d_ws;                  // [6][TC] = 12.6 MB
    float* G  = Cb + (size_t)6 * TC;           // [6][NB] = 48 KB

    hipLaunchKernelGGL(k_agg,   dim3(NB), dim3(CPB), 0, stream, x, cl, Cb, G);
    hipLaunchKernelGGL(k_apply, dim3(NB), dim3(CPB), 0, stream, x, cl, Cb, G, out);
}